// Round 3
// baseline (382.489 us; speedup 1.0000x reference)
//
#include <hip/hip_runtime.h>

typedef __attribute__((ext_vector_type(4))) float f32x4;
typedef __attribute__((ext_vector_type(8))) short s16x8;
typedef __attribute__((ext_vector_type(2))) unsigned int u32x2;
typedef __attribute__((ext_vector_type(4))) unsigned int u32x4;

#define X_ELEMS 25690112          // 32*64*112*112
#define X_F4    6422528           // X_ELEMS/4
#define HW 112
#define PW 116                    // padded row width (2 zero cols each side)
#define PPLANE (112*116)          // 12992 shorts per padded channel plane
#define CHW (64*112*112)          // 802816

// q = I * 2^(e-7), |I|<=256 -> exactly representable in bf16; low 16 fp32 bits are 0.
__device__ __forceinline__ unsigned short f32_to_bf16_exact(float q) {
    return (unsigned short)(__float_as_uint(q) >> 16);
}

// pack bf16(a) into low short, bf16(b) into high short (one v_perm_b32)
__device__ __forceinline__ unsigned int pack_bf16x2(float a, float b) {
    return __builtin_amdgcn_perm(__float_as_uint(b), __float_as_uint(a), 0x07060302u);
}

__device__ __forceinline__ void scale_from_max(float m, float& scale, float& inv) {
    if (m > 0.f) {
        int e = (int)((__float_as_uint(m) >> 23) & 0xFF) - 127;  // exact floor(log2(m)) for normal m
        scale = __builtin_ldexpf(1.0f, e - 7);
        inv   = __builtin_ldexpf(1.0f, 7 - e);
    } else { scale = 0.f; inv = 0.f; }
}

// ---- Q1 (fused): read x ONCE, group-max via LDS, quantize in-register,
// write xq = bf16 NCHW with row padding [plane][112][116] (pad cols zeroed).
// Block 2788 quantizes the weights instead ([pos=9][k=64][c=64] bf16). ----
__global__ __launch_bounds__(256) void q1_quant(const float* __restrict__ x,
                                                const float* __restrict__ w,
                                                unsigned short* __restrict__ xq,
                                                unsigned short* __restrict__ wt) {
    __shared__ float lmax[2304];
    __shared__ float lsc[256];
    __shared__ float linv[256];
    const int b = blockIdx.x, tid = threadIdx.x;

    if (b == 2788) {                              // ---- weight path: 1024 groups of 36
        #pragma unroll 1
        for (int rep = 0; rep < 4; ++rep) {
            int g = rep * 256 + tid;
            const float4* p = (const float4*)w + g * 9;
            float vv[36]; float m = 0.f;
            #pragma unroll
            for (int i = 0; i < 9; ++i) {
                float4 v = p[i];
                vv[i*4+0]=v.x; vv[i*4+1]=v.y; vv[i*4+2]=v.z; vv[i*4+3]=v.w;
                m = fmaxf(m, fmaxf(fmaxf(fabsf(v.x), fabsf(v.y)), fmaxf(fabsf(v.z), fabsf(v.w))));
            }
            float s, inv; scale_from_max(m, s, inv);
            #pragma unroll
            for (int j = 0; j < 36; ++j) {
                int flat = g * 36 + j;
                int k = flat / 576, rem = flat % 576;
                int c = rem / 9, pp = rem % 9;
                float q = rintf(vv[j] * inv) * s;
                wt[pp * 4096 + k * 64 + c] = f32_to_bf16_exact(q);
            }
        }
        return;
    }

    // ---- x path: block owns 256 groups = 9216 floats = 2304 float4 (contiguous)
    long base4 = (long)b * 2304;
    float4 vv[9];
    #pragma unroll
    for (int it = 0; it < 9; ++it) {
        int i = it * 256 + tid;
        long g4 = base4 + i;
        float4 v = {0.f, 0.f, 0.f, 0.f};
        if (g4 < X_F4) v = ((const float4*)x)[g4];
        vv[it] = v;
        lmax[i] = fmaxf(fmaxf(fabsf(v.x), fabsf(v.y)), fmaxf(fabsf(v.z), fabsf(v.w)));
    }
    __syncthreads();
    {
        float m = 0.f; int o = tid * 9;           // stride-9 over 32 banks: conflict-light
        #pragma unroll
        for (int j = 0; j < 9; ++j) m = fmaxf(m, lmax[o + j]);
        float s, inv; scale_from_max(m, s, inv);
        lsc[tid] = s; linv[tid] = inv;
    }
    __syncthreads();
    #pragma unroll
    for (int it = 0; it < 9; ++it) {
        int i = it * 256 + tid;
        int g4 = (int)base4 + i;
        if (g4 < X_F4) {
            int lg = i / 9;                       // float4 never crosses a group (36 % 4 == 0)
            float s = lsc[lg], inv = linv[lg];
            float4 v = vv[it];
            u32x2 o;
            o.x = pack_bf16x2(rintf(v.x * inv) * s, rintf(v.y * inv) * s);
            o.y = pack_bf16x2(rintf(v.z * inv) * s, rintf(v.w * inv) * s);
            int flat = g4 * 4;                    // NCHW element index (w % 4 == 0, 112 % 4 == 0)
            int plane = flat / 12544;
            int rw = flat - plane * 12544;
            int h = rw / 112, ww = rw - h * 112;
            int rowb = plane * PPLANE + h * PW;
            *(u32x2*)(xq + rowb + 2 + ww) = o;    // 8B store, 4B-aligned (HW-ok)
            if (ww == 0)        *(unsigned int*)(xq + rowb) = 0u;        // left pad cols 0-1
            else if (ww == 108) *(unsigned int*)(xq + rowb + 114) = 0u;  // right pad cols 114-115
        }
    }
}

// LDS address with XOR-swizzled 16B c-octet slot: bank cluster = f(pix, oct) covers
// all 8 clusters across a wave (plain layout collapses to 2 -> ~4x conflict).
__device__ __forceinline__ int swz(int pix, int oct) {
    return pix * 72 + (((oct) ^ ((pix >> 3) & 7)) << 3);
}

// ---- conv: tile 8h x 28w x 64k, grid 1792, 3 blocks/CU (no spills: B held
// one cs-half at a time = 72 VGPR, reloaded from L2-hot wt between halves). ----
__global__ __launch_bounds__(256, 3) void conv_mfma(const unsigned short* __restrict__ xq,
                                                    const unsigned short* __restrict__ wt,
                                                    const float* __restrict__ bias,
                                                    float* __restrict__ out) {
    __shared__ unsigned short xs[360 * 72];       // 10 rows x 36 cols halo, 72-short pixel stride
    const int tid = threadIdx.x;
    const int wave = tid >> 6, lane = tid & 63;
    const int wl = lane & 15, quad = lane >> 4;
    const int kg = wave & 1, mg = wave >> 1;
    int b = blockIdx.x;
    b = (b & 7) * 224 + (b >> 3);                 // XCD-chunked swizzle (1792 = 8*224, bijective)
    const int n = b / 56, rem = b % 56;
    const int h0 = (rem >> 2) * 8, w0 = (rem & 3) * 28;

    // stage: 320 tasks = (c-octet 8) x (row 10) x (w-oct 4); task: 8 b128 loads
    // (8 channels x 8 w), 8x8 register transpose (32 perms), 8 ds_write_b128.
    #pragma unroll
    for (int tt = 0; tt < 2; ++tt) {
        int t = tt * 256 + tid;
        if (t < 320) {
            int oct = t / 40;
            int rm = t - oct * 40;
            int r = rm >> 2, wq = rm & 3;
            int hh = h0 - 1 + r;
            int c0 = w0 + wq * 8;                 // padded col of chunk start (covers w0-2..w0+29)
            u32x4 v[8];
            if (hh >= 0 && hh < HW) {
                const unsigned short* src = xq + (n * 64 + oct * 8) * PPLANE + hh * PW + c0;
                #pragma unroll
                for (int j = 0; j < 8; ++j)
                    v[j] = *(const u32x4*)(src + j * PPLANE);
            } else {
                #pragma unroll
                for (int j = 0; j < 8; ++j) v[j] = (u32x4){0u, 0u, 0u, 0u};
            }
            int pix0 = r * 36 + wq * 8 + 2;       // halo cols 2..33 (reads touch 3..32)
            #pragma unroll
            for (int d = 0; d < 8; ++d) {
                unsigned int sel = (d & 1) ? 0x07060302u : 0x05040100u;
                int k = d >> 1;
                u32x4 o;
                o.x = __builtin_amdgcn_perm(v[1][k], v[0][k], sel);
                o.y = __builtin_amdgcn_perm(v[3][k], v[2][k], sel);
                o.z = __builtin_amdgcn_perm(v[5][k], v[4][k], sel);
                o.w = __builtin_amdgcn_perm(v[7][k], v[6][k], sel);
                *(u32x4*)&xs[swz(pix0 + d, oct)] = o;
            }
        }
    }

    // B fragments for cs=0 only (72 VGPR, not 144): prefetch overlaps staging.
    s16x8 Bf[9][2];
    #pragma unroll
    for (int p = 0; p < 9; ++p)
        #pragma unroll
        for (int j = 0; j < 2; ++j)
            Bf[p][j] = *(const s16x8*)(wt + p * 4096 +
                            ((kg * 2 + j) * 16 + wl) * 64 + quad * 8);

    float bv[2];
    #pragma unroll
    for (int j = 0; j < 2; ++j) bv[j] = bias[kg * 32 + j * 16 + wl];

    int pixb[7];
    #pragma unroll
    for (int mti = 0; mti < 7; ++mti) {
        int m = (mg * 7 + mti) * 16 + wl;
        pixb[mti] = (m / 28) * 36 + (m % 28) + 3;           // col offset +3 in 36-wide halo
    }

    __syncthreads();

    f32x4 acc[7][2];
    f32x4 zero = {0.f, 0.f, 0.f, 0.f};
    #pragma unroll
    for (int mti = 0; mti < 7; ++mti) { acc[mti][0] = zero; acc[mti][1] = zero; }

    #pragma unroll 1                              // keep halves sequential: one Bf set live
    for (int cs = 0; cs < 2; ++cs) {
        if (cs) {                                 // reload B for cs=1 (wt is L2-hot)
            #pragma unroll
            for (int p = 0; p < 9; ++p)
                #pragma unroll
                for (int j = 0; j < 2; ++j)
                    Bf[p][j] = *(const s16x8*)(wt + p * 4096 +
                                    ((kg * 2 + j) * 16 + wl) * 64 + 32 + quad * 8);
        }
        #pragma unroll
        for (int p = 0; p < 9; ++p) {
            const int dpix = (p / 3) * 36 + (p % 3);
            #pragma unroll
            for (int mti = 0; mti < 7; ++mti) {
                s16x8 A = *(const s16x8*)&xs[swz(pixb[mti] + dpix, cs * 4 + quad)];
                acc[mti][0] = __builtin_amdgcn_mfma_f32_16x16x32_bf16(A, Bf[p][0], acc[mti][0], 0, 0, 0);
                acc[mti][1] = __builtin_amdgcn_mfma_f32_16x16x32_bf16(A, Bf[p][1], acc[mti][1], 0, 0, 0);
            }
        }
    }

    // epilogue: direct coalesced float4 stores (eofs computed on the fly)
    int obase = n * CHW + h0 * HW + w0;
    #pragma unroll
    for (int mti = 0; mti < 7; ++mti) {
        int m0 = (mg * 7 + mti) * 16 + quad * 4;            // 28%4==0 -> float4 stays in-row
        int eofs = (m0 / 28) * HW + (m0 % 28);
        #pragma unroll
        for (int j = 0; j < 2; ++j) {
            f32x4 v = acc[mti][j];
            v.x += bv[j]; v.y += bv[j]; v.z += bv[j]; v.w += bv[j];
            *(f32x4*)(out + obase + (kg * 32 + j * 16 + wl) * 12544 + eofs) = v;
        }
    }
}

extern "C" void kernel_launch(void* const* d_in, const int* in_sizes, int n_in,
                              void* d_out, int out_size, void* d_ws, size_t ws_size,
                              hipStream_t stream) {
    const float* x    = (const float*)d_in[0];
    const float* w    = (const float*)d_in[1];
    const float* bias = (const float*)d_in[2];
    float* out = (float*)d_out;
    char* ws = (char*)d_ws;
    unsigned short* xq = (unsigned short*)ws;                   // 32*64*112*116*2 = 53,215,232 B
    unsigned short* wt = (unsigned short*)(ws + 53215232);      //     73,728 B

    hipLaunchKernelGGL(q1_quant,  dim3(2789), dim3(256), 0, stream, x, w, xq, wt);
    hipLaunchKernelGGL(conv_mfma, dim3(1792), dim3(256), 0, stream, xq, wt, bias, out);
}

// Round 4
// 258.278 us; speedup vs baseline: 1.4809x; 1.4809x over previous
//
#include <hip/hip_runtime.h>

typedef __attribute__((ext_vector_type(4))) float f32x4;
typedef __attribute__((ext_vector_type(8))) short s16x8;
typedef __attribute__((ext_vector_type(2))) unsigned int u32x2;
typedef __attribute__((ext_vector_type(4))) unsigned int u32x4;

#define X_ELEMS 25690112          // 32*64*112*112
#define X_F4    6422528           // X_ELEMS/4
#define HW 112
#define PW 120                    // padded row width: 4 zero cols left, 4 right
#define PPLANE (112*120)          // 13440 shorts per padded channel plane
#define CHW (64*112*112)          // 802816

// q = I * 2^(e-7), |I|<=256 -> exactly representable in bf16; low 16 fp32 bits are 0.
__device__ __forceinline__ unsigned short f32_to_bf16_exact(float q) {
    return (unsigned short)(__float_as_uint(q) >> 16);
}

// pack bf16(a) into low short, bf16(b) into high short (one v_perm_b32)
__device__ __forceinline__ unsigned int pack_bf16x2(float a, float b) {
    return __builtin_amdgcn_perm(__float_as_uint(b), __float_as_uint(a), 0x07060302u);
}

__device__ __forceinline__ void scale_from_max(float m, float& scale, float& inv) {
    if (m > 0.f) {
        int e = (int)((__float_as_uint(m) >> 23) & 0xFF) - 127;  // exact floor(log2(m)) for normal m
        scale = __builtin_ldexpf(1.0f, e - 7);
        inv   = __builtin_ldexpf(1.0f, 7 - e);
    } else { scale = 0.f; inv = 0.f; }
}

// ---- Q1 (fused): read x ONCE, group-max via LDS, quantize in-register,
// write xq = bf16 NCHW with row padding [plane][112][120] (pad cols zeroed).
// All stores 8B-aligned (left pad = 4 shorts). Block 2788 quantizes weights. ----
__global__ __launch_bounds__(256) void q1_quant(const float* __restrict__ x,
                                                const float* __restrict__ w,
                                                unsigned short* __restrict__ xq,
                                                unsigned short* __restrict__ wt) {
    __shared__ float lmax[2304];
    __shared__ float lsc[256];
    __shared__ float linv[256];
    const int b = blockIdx.x, tid = threadIdx.x;

    if (b == 2788) {                              // ---- weight path: 1024 groups of 36
        #pragma unroll 1
        for (int rep = 0; rep < 4; ++rep) {
            int g = rep * 256 + tid;
            const float4* p = (const float4*)w + g * 9;
            float vv[36]; float m = 0.f;
            #pragma unroll
            for (int i = 0; i < 9; ++i) {
                float4 v = p[i];
                vv[i*4+0]=v.x; vv[i*4+1]=v.y; vv[i*4+2]=v.z; vv[i*4+3]=v.w;
                m = fmaxf(m, fmaxf(fmaxf(fabsf(v.x), fabsf(v.y)), fmaxf(fabsf(v.z), fabsf(v.w))));
            }
            float s, inv; scale_from_max(m, s, inv);
            #pragma unroll
            for (int j = 0; j < 36; ++j) {
                int flat = g * 36 + j;
                int k = flat / 576, rem = flat % 576;
                int c = rem / 9, pp = rem % 9;
                float q = rintf(vv[j] * inv) * s;
                wt[pp * 4096 + k * 64 + c] = f32_to_bf16_exact(q);
            }
        }
        return;
    }

    // ---- x path: block owns 256 groups = 9216 floats = 2304 float4 (contiguous)
    long base4 = (long)b * 2304;
    float4 vv[9];
    #pragma unroll
    for (int it = 0; it < 9; ++it) {
        int i = it * 256 + tid;
        long g4 = base4 + i;
        float4 v = {0.f, 0.f, 0.f, 0.f};
        if (g4 < X_F4) v = ((const float4*)x)[g4];
        vv[it] = v;
        lmax[i] = fmaxf(fmaxf(fabsf(v.x), fabsf(v.y)), fmaxf(fabsf(v.z), fabsf(v.w)));
    }
    __syncthreads();
    {
        float m = 0.f; int o = tid * 9;           // stride-9 over 32 banks: conflict-light
        #pragma unroll
        for (int j = 0; j < 9; ++j) m = fmaxf(m, lmax[o + j]);
        float s, inv; scale_from_max(m, s, inv);
        lsc[tid] = s; linv[tid] = inv;
    }
    __syncthreads();
    #pragma unroll
    for (int it = 0; it < 9; ++it) {
        int i = it * 256 + tid;
        int g4 = (int)base4 + i;
        if (g4 < X_F4) {
            int lg = i / 9;                       // float4 never crosses a group (36 % 4 == 0)
            float s = lsc[lg], inv = linv[lg];
            float4 v = vv[it];
            u32x2 o;
            o.x = pack_bf16x2(rintf(v.x * inv) * s, rintf(v.y * inv) * s);
            o.y = pack_bf16x2(rintf(v.z * inv) * s, rintf(v.w * inv) * s);
            int flat = g4 * 4;                    // NCHW element index (w % 4 == 0, 112 % 4 == 0)
            int plane = flat / 12544;
            int rw = flat - plane * 12544;
            int h = rw / 112, ww = rw - h * 112;
            int rowb = plane * PPLANE + h * PW;
            *(u32x2*)(xq + rowb + 4 + ww) = o;    // 8B store, 8B-aligned
            if (ww == 0)        *(u32x2*)(xq + rowb) = (u32x2){0u, 0u};        // pad cols 0-3
            else if (ww == 108) *(u32x2*)(xq + rowb + 116) = (u32x2){0u, 0u};  // pad cols 116-119
        }
    }
}

// LDS address with XOR-swizzled 16B c-octet slot: bank cluster = f(pix, oct) covers
// all 8 clusters across a wave (plain layout collapses to 2 -> ~4x conflict).
__device__ __forceinline__ int swz(int pix, int oct) {
    return pix * 72 + (((oct) ^ ((pix >> 3) & 7)) << 3);
}

// ---- conv: tile 8h x 28w x 64k, grid 1792, 2 blocks/CU (the only config that
// never spills: VGPR 120-160 incl. full Bf[9][2][2] preload). b128 staging from
// padded-NCHW xq, 8x8 register transpose (v_perm) into swizzled LDS. ----
__global__ __launch_bounds__(256, 2) void conv_mfma(const unsigned short* __restrict__ xq,
                                                    const unsigned short* __restrict__ wt,
                                                    const float* __restrict__ bias,
                                                    float* __restrict__ out) {
    __shared__ unsigned short xs[360 * 72];       // 10 rows x 36 cols halo, 72-short pixel stride
    const int tid = threadIdx.x;
    const int wave = tid >> 6, lane = tid & 63;
    const int wl = lane & 15, quad = lane >> 4;
    const int kg = wave & 1, mg = wave >> 1;
    int b = blockIdx.x;
    b = (b & 7) * 224 + (b >> 3);                 // XCD-chunked swizzle (1792 = 8*224, bijective)
    const int n = b / 56, rem = b % 56;
    const int h0 = (rem >> 2) * 8, w0 = (rem & 3) * 28;

    // stage: 320 tasks = (c-octet 8) x (row 10) x (w-oct 4); task: 8 b128 loads
    // (8 channels x 8 w), 8x8 register transpose (32 perms), 8 ds_write_b128.
    #pragma unroll
    for (int tt = 0; tt < 2; ++tt) {
        int t = tt * 256 + tid;
        if (t < 320) {
            int oct = t / 40;
            int rm = t - oct * 40;
            int r = rm >> 2, wq = rm & 3;
            int hh = h0 - 1 + r;
            int c0 = w0 + 2 + wq * 8;             // padded col of data col (w0-2 + wq*8)
            u32x4 v[8];
            if (hh >= 0 && hh < HW) {
                const unsigned short* src = xq + (n * 64 + oct * 8) * PPLANE + hh * PW + c0;
                #pragma unroll
                for (int j = 0; j < 8; ++j)
                    v[j] = *(const u32x4*)(src + j * PPLANE);
            } else {
                #pragma unroll
                for (int j = 0; j < 8; ++j) v[j] = (u32x4){0u, 0u, 0u, 0u};
            }
            int pix0 = r * 36 + wq * 8 + 2;       // halo cols 2..33 (reads touch 3..32)
            #pragma unroll
            for (int d = 0; d < 8; ++d) {
                unsigned int sel = (d & 1) ? 0x07060302u : 0x05040100u;
                int k = d >> 1;
                u32x4 o;
                o.x = __builtin_amdgcn_perm(v[1][k], v[0][k], sel);
                o.y = __builtin_amdgcn_perm(v[3][k], v[2][k], sel);
                o.z = __builtin_amdgcn_perm(v[5][k], v[4][k], sel);
                o.w = __builtin_amdgcn_perm(v[7][k], v[6][k], sel);
                *(u32x4*)&xs[swz(pix0 + d, oct)] = o;
            }
        }
    }

    // gather this wave's B fragments (32 k-channels, both cs halves): overlaps staging
    s16x8 Bf[9][2][2];
    #pragma unroll
    for (int p = 0; p < 9; ++p)
        #pragma unroll
        for (int cs = 0; cs < 2; ++cs)
            #pragma unroll
            for (int j = 0; j < 2; ++j)
                Bf[p][cs][j] = *(const s16x8*)(wt + p * 4096 +
                                ((kg * 2 + j) * 16 + wl) * 64 + cs * 32 + quad * 8);

    float bv[2];
    #pragma unroll
    for (int j = 0; j < 2; ++j) bv[j] = bias[kg * 32 + j * 16 + wl];

    int pixb[7];
    #pragma unroll
    for (int mti = 0; mti < 7; ++mti) {
        int m = (mg * 7 + mti) * 16 + wl;
        pixb[mti] = (m / 28) * 36 + (m % 28) + 3;           // col offset +3 in 36-wide halo
    }

    __syncthreads();

    f32x4 acc[7][2];
    f32x4 zero = {0.f, 0.f, 0.f, 0.f};
    #pragma unroll
    for (int mti = 0; mti < 7; ++mti) { acc[mti][0] = zero; acc[mti][1] = zero; }

    #pragma unroll
    for (int p = 0; p < 9; ++p) {
        const int dpix = (p / 3) * 36 + (p % 3);
        #pragma unroll
        for (int cs = 0; cs < 2; ++cs) {
            #pragma unroll
            for (int mti = 0; mti < 7; ++mti) {
                s16x8 A = *(const s16x8*)&xs[swz(pixb[mti] + dpix, cs * 4 + quad)];
                acc[mti][0] = __builtin_amdgcn_mfma_f32_16x16x32_bf16(A, Bf[p][cs][0], acc[mti][0], 0, 0, 0);
                acc[mti][1] = __builtin_amdgcn_mfma_f32_16x16x32_bf16(A, Bf[p][cs][1], acc[mti][1], 0, 0, 0);
            }
        }
    }

    // epilogue: direct coalesced float4 stores (offsets computed on the fly)
    int obase = n * CHW + h0 * HW + w0;
    #pragma unroll
    for (int mti = 0; mti < 7; ++mti) {
        int m0 = (mg * 7 + mti) * 16 + quad * 4;            // 28%4==0 -> float4 stays in-row
        int eofs = (m0 / 28) * HW + (m0 % 28);
        #pragma unroll
        for (int j = 0; j < 2; ++j) {
            f32x4 v = acc[mti][j];
            v.x += bv[j]; v.y += bv[j]; v.z += bv[j]; v.w += bv[j];
            *(f32x4*)(out + obase + (kg * 32 + j * 16 + wl) * 12544 + eofs) = v;
        }
    }
}

extern "C" void kernel_launch(void* const* d_in, const int* in_sizes, int n_in,
                              void* d_out, int out_size, void* d_ws, size_t ws_size,
                              hipStream_t stream) {
    const float* x    = (const float*)d_in[0];
    const float* w    = (const float*)d_in[1];
    const float* bias = (const float*)d_in[2];
    float* out = (float*)d_out;
    char* ws = (char*)d_ws;
    unsigned short* xq = (unsigned short*)ws;                   // 32*64*112*120*2 = 55,050,240 B
    unsigned short* wt = (unsigned short*)(ws + 55050240);      //     73,728 B

    hipLaunchKernelGGL(q1_quant,  dim3(2789), dim3(256), 0, stream, x, w, xq, wt);
    hipLaunchKernelGGL(conv_mfma, dim3(1792), dim3(256), 0, stream, xq, wt, bias, out);
}